// Round 3
// baseline (233.797 us; speedup 1.0000x reference)
//
#include <hip/hip_runtime.h>
#include <hip/hip_bf16.h>
#include <math.h>

#define II 1024
#define HH 1024
#define LL 16384
#define NB 256
#define NT 1024
#define EPSF 1e-8f

__device__ __forceinline__ float wred_sum(float v) {
    #pragma unroll
    for (int o = 32; o; o >>= 1) v += __shfl_down(v, o);
    return v;
}
__device__ __forceinline__ float wred_max(float v) {
    #pragma unroll
    for (int o = 32; o; o >>= 1) v = fmaxf(v, __shfl_down(v, o));
    return v;
}

// Device-scope counting barrier. One slot per phase; slots zeroed by
// init_kernel every call, each block adds exactly 1 per slot -> deterministic.
__device__ __forceinline__ void grid_barrier(int* cnt) {
    __syncthreads();
    if (threadIdx.x == 0) {
        __threadfence();  // release our block's global writes (agent scope)
        __hip_atomic_fetch_add(cnt, 1, __ATOMIC_ACQ_REL, __HIP_MEMORY_SCOPE_AGENT);
        while (__hip_atomic_load(cnt, __ATOMIC_ACQUIRE, __HIP_MEMORY_SCOPE_AGENT) < NB)
            __builtin_amdgcn_s_sleep(2);
        __threadfence();  // acquire other blocks' writes
    }
    __syncthreads();
}

__global__ void init_kernel(int* cnt) {
    if (threadIdx.x < 16) cnt[threadIdx.x] = 0;
}

// 256 blocks x 1024 threads: 1 block/CU, 16 waves/block (4/SIMD).
// Co-residency: LDS ~4.8 KB, VGPR capped <=128 by launch_bounds -> worst-case
// packing capacity >= 256 blocks, so the atomic barrier cannot deadlock.
__global__ __launch_bounds__(NT, 4) void fused_kernel(
    const int* __restrict__ token, const float* __restrict__ hidden,
    const float* __restrict__ enc, const float* __restrict__ emb,
    const float* __restrict__ attn_w, const float* __restrict__ attn_b,
    const float* __restrict__ comb_w, const float* __restrict__ comb_b,
    const float* __restrict__ w_ih, const float* __restrict__ w_hh,
    const float* __restrict__ b_ih, const float* __restrict__ b_hh,
    const float* __restrict__ fc2_w, const float* __restrict__ fc2_b,
    const float* __restrict__ out_w, const float* __restrict__ out_b,
    float* __restrict__ ws, float* __restrict__ out) {
    // ws map (floats)
    float* q    = ws;            // 1024
    float* gh   = ws + 1024;     // 3072
    float* x    = ws + 4096;     // 1024
    float* gi   = ws + 5120;     // 3072
    float* aa   = ws + 8192;     // 1024
    float* qssq = ws + 9216;     // 256
    float* pmax = ws + 9472;     // 256
    float* psum = ws + 9728;     // 256
    float* fbuf = ws + 9984;     // 64
    float* part = ws + 10240;    // 256*1024
    int*   cnt  = (int*)(ws + 272384);  // 16 ints

    float* out_scalar = out;
    float* h_new      = out + 1;
    float* attn_wout  = out + 1 + HH;

    __shared__ float s_red[16];
    __shared__ float s_sims[64];
    __shared__ float s_w[64];
    __shared__ float s_h[1024];
    __shared__ float s_b;

    const int b = blockIdx.x, t = threadIdx.x;
    const int wv = t >> 6, lane = t & 63;
    const float* er = emb + (size_t)token[0] * II;

    // ---- Phase A: q = attn_w.[emb|h0]+attn_b (waves 0..1023 = blocks 0..63)
    //               gh = w_hh.h0+b_hh          (waves 1024..4095) ----
    {
        int gw = b * 16 + wv;
        float acc = 0.f;
        if (gw < HH) {
            const float* row = attn_w + (size_t)gw * (II + HH);
            for (int k = lane * 4; k < II + HH; k += 256) {
                float4 w4 = *(const float4*)(row + k);
                const float* src = (k < II) ? (er + k) : (hidden + (k - II));
                float4 x4 = *(const float4*)src;
                acc += w4.x * x4.x + w4.y * x4.y + w4.z * x4.z + w4.w * x4.w;
            }
            acc = wred_sum(acc);
            if (lane == 0) { float v = acc + attn_b[gw]; q[gw] = v; s_red[wv] = v * v; }
        } else {
            int r = gw - HH;
            const float* row = w_hh + (size_t)r * HH;
            for (int k = lane * 4; k < HH; k += 256) {
                float4 w4 = *(const float4*)(row + k);
                float4 x4 = *(const float4*)(hidden + k);
                acc += w4.x * x4.x + w4.y * x4.y + w4.z * x4.z + w4.w * x4.w;
            }
            acc = wred_sum(acc);
            if (lane == 0) { gh[r] = acc + b_hh[r]; s_red[wv] = 0.f; }
        }
        __syncthreads();
        if (t == 0) {
            float s = 0.f;
            for (int i = 0; i < 16; ++i) s += s_red[i];
            qssq[b] = s;  // partial sum-of-squares of q (0 for gh blocks)
        }
    }
    grid_barrier(cnt + 0);

    // ---- Phase B: sims for rows [b*64, b*64+64), kept in LDS ----
    {
        float v = (t < NB) ? qssq[t] : 0.f;
        v = wred_sum(v);
        if (lane == 0) s_red[wv] = v;
        __syncthreads();
        if (t == 0) {
            float s = 0.f;
            for (int i = 0; i < 16; ++i) s += s_red[i];
            s_b = fmaxf(sqrtf(s), EPSF);
        }
        __syncthreads();
        float qn = s_b;
        for (int j = 0; j < 4; ++j) {
            int r = b * 64 + wv * 4 + j;
            const float* row = enc + (size_t)r * HH;
            float dv = 0.f, sv = 0.f;
            for (int k = lane * 4; k < HH; k += 256) {
                float4 e4 = *(const float4*)(row + k);
                float4 q4 = *(const float4*)(q + k);  // q is L1-hot
                dv += e4.x * q4.x + e4.y * q4.y + e4.z * q4.z + e4.w * q4.w;
                sv += e4.x * e4.x + e4.y * e4.y + e4.z * e4.z + e4.w * e4.w;
            }
            #pragma unroll
            for (int o = 32; o; o >>= 1) {
                dv += __shfl_down(dv, o);
                sv += __shfl_down(sv, o);
            }
            if (lane == 0) {
                float en = fmaxf(sqrtf(sv), EPSF);
                s_sims[wv * 4 + j] = dv / (qn * en);
            }
        }
        __syncthreads();
        if (wv == 0) {  // threads 0..63 == wave 0 cover s_sims exactly
            float m = s_sims[lane];
            m = wred_max(m);
            if (lane == 0) pmax[b] = m;
        }
    }
    grid_barrier(cnt + 1);

    // ---- Phase C: global max; exp; psum; UNNORMALIZED colsum partial ----
    {
        float mv = (t < NB) ? pmax[t] : -INFINITY;
        mv = wred_max(mv);
        if (lane == 0) s_red[wv] = mv;
        __syncthreads();
        if (t == 0) {
            float m = -INFINITY;
            for (int i = 0; i < 16; ++i) m = fmaxf(m, s_red[i]);
            s_b = m;
        }
        __syncthreads();
        float m = s_b;
        if (t < 64) s_w[t] = expf(s_sims[t] - m);
        __syncthreads();
        if (wv == 0) {
            float sv = s_w[lane];
            sv = wred_sum(sv);
            if (lane == 0) psum[b] = sv;
        }
        // colsum over this block's 64 rows; thread t owns column t.
        const float* base = enc + (size_t)b * 64 * HH;
        float acc = 0.f;
        #pragma unroll 8
        for (int r = 0; r < 64; ++r)
            acc = fmaf(s_w[r], base[(size_t)r * HH + t], acc);
        part[(size_t)b * HH + t] = acc;
    }
    grid_barrier(cnt + 2);

    // ---- Phase D: global sum; attn weights out; reduce partials -> aa ----
    {
        float sv = (t < NB) ? psum[t] : 0.f;
        sv = wred_sum(sv);
        if (lane == 0) s_red[wv] = sv;
        __syncthreads();
        if (t == 0) {
            float s = 0.f;
            for (int i = 0; i < 16; ++i) s += s_red[i];
            s_b = 1.f / s;
        }
        __syncthreads();
        float inv = s_b;
        if (t < 64) attn_wout[b * 64 + t] = s_w[t] * inv;
        // reduce 256 partial chunks for cols b*4 .. b*4+3 (normalization folded in)
        int col = b * 4 + (t >> 8);
        float v = part[(size_t)(t & 255) * HH + col];
        v = wred_sum(v);
        if (lane == 0) s_red[wv] = v;
        __syncthreads();
        if (t < 4) {
            float s = s_red[t * 4] + s_red[t * 4 + 1] + s_red[t * 4 + 2] + s_red[t * 4 + 3];
            aa[b * 4 + t] = s * inv;
        }
    }
    grid_barrier(cnt + 3);

    // ---- Phase E: x = relu(comb_w.[emb|aa]+comb_b); 4 waves per row ----
    {
        int j = wv >> 2, ch = wv & 3;
        int r = b * 4 + j;
        const float* row = comb_w + (size_t)r * (II + HH) + ch * 512;
        const float* src = (ch < 2) ? (er + ch * 512) : (aa + (ch - 2) * 512);
        int k = lane * 8;
        float4 a0 = *(const float4*)(row + k);
        float4 a1 = *(const float4*)(row + k + 4);
        float4 s0 = *(const float4*)(src + k);
        float4 s1 = *(const float4*)(src + k + 4);
        float acc = a0.x * s0.x + a0.y * s0.y + a0.z * s0.z + a0.w * s0.w +
                    a1.x * s1.x + a1.y * s1.y + a1.z * s1.z + a1.w * s1.w;
        acc = wred_sum(acc);
        if (lane == 0) s_red[wv] = acc;
        __syncthreads();
        if (t < 4) {
            float s = s_red[t * 4] + s_red[t * 4 + 1] + s_red[t * 4 + 2] + s_red[t * 4 + 3];
            x[b * 4 + t] = fmaxf(s + comb_b[b * 4 + t], 0.f);
        }
    }
    grid_barrier(cnt + 4);

    // ---- Phase F: gi rows b*12 .. b*12+11 ----
    {
        if (wv < 12) {
            int r = b * 12 + wv;
            const float* row = w_ih + (size_t)r * II;
            float acc = 0.f;
            for (int k = lane * 4; k < II; k += 256) {
                float4 w4 = *(const float4*)(row + k);
                float4 x4 = *(const float4*)(x + k);
                acc += w4.x * x4.x + w4.y * x4.y + w4.z * x4.z + w4.w * x4.w;
            }
            acc = wred_sum(acc);
            if (lane == 0) gi[r] = acc + b_ih[r];
        }
    }
    grid_barrier(cnt + 5);

    // ---- Phase G: GRU (blocks 0..63, redundant) + fc2 row b ----
    {
        if (b < 64) {
            float gr = gi[t],          hr = gh[t];
            float gz = gi[HH + t],     hz = gh[HH + t];
            float gn = gi[2 * HH + t], hn = gh[2 * HH + t];
            float rg = 1.f / (1.f + expf(-(gr + hr)));
            float zg = 1.f / (1.f + expf(-(gz + hz)));
            float ng = tanhf(gn + rg * hn);
            float h = (1.f - zg) * ng + zg * hidden[t];
            s_h[t] = h;
            if (b == 0) h_new[t] = h;
            __syncthreads();
            const float* row = fc2_w + (size_t)b * HH;
            float acc = row[t] * s_h[t];
            acc = wred_sum(acc);
            if (lane == 0) s_red[wv] = acc;
            __syncthreads();
            if (t == 0) {
                float s = 0.f;
                for (int i = 0; i < 16; ++i) s += s_red[i];
                fbuf[b] = fmaxf(s + fc2_b[b], 0.f);
            }
        }
    }
    grid_barrier(cnt + 6);

    // ---- Phase H: out scalar ----
    if (b == 0 && wv == 0) {
        float v = fbuf[lane] * out_w[lane];
        v = wred_sum(v);
        if (lane == 0) out_scalar[0] = v + out_b[0];
    }
}

extern "C" void kernel_launch(void* const* d_in, const int* in_sizes, int n_in,
                              void* d_out, int out_size, void* d_ws,
                              size_t ws_size, hipStream_t stream) {
    const int*   token  = (const int*)d_in[0];
    const float* hidden = (const float*)d_in[1];
    const float* enc    = (const float*)d_in[2];
    const float* emb    = (const float*)d_in[3];
    const float* attn_w = (const float*)d_in[4];
    const float* attn_b = (const float*)d_in[5];
    const float* comb_w = (const float*)d_in[6];
    const float* comb_b = (const float*)d_in[7];
    const float* w_ih   = (const float*)d_in[8];
    const float* w_hh   = (const float*)d_in[9];
    const float* b_ih   = (const float*)d_in[10];
    const float* b_hh   = (const float*)d_in[11];
    const float* fc2_w  = (const float*)d_in[12];
    const float* fc2_b  = (const float*)d_in[13];
    const float* out_w  = (const float*)d_in[14];
    const float* out_b  = (const float*)d_in[15];

    float* ws = (float*)d_ws;
    int* cnt = (int*)(ws + 272384);

    // zero the barrier slots (replays inherit 256s from the previous call)
    init_kernel<<<1, 64, 0, stream>>>(cnt);
    fused_kernel<<<NB, NT, 0, stream>>>(token, hidden, enc, emb, attn_w, attn_b,
                                        comb_w, comb_b, w_ih, w_hh, b_ih, b_hh,
                                        fc2_w, fc2_b, out_w, out_b, ws,
                                        (float*)d_out);
}

// Round 4
// 78.140 us; speedup vs baseline: 2.9920x; 2.9920x over previous
//
#include <hip/hip_runtime.h>
#include <hip/hip_bf16.h>
#include <math.h>

#define II 1024
#define HH 1024
#define LL 16384
#define EPSF 1e-8f

__device__ __forceinline__ float wred_sum(float v) {
    #pragma unroll
    for (int o = 32; o; o >>= 1) v += __shfl_down(v, o);
    return v;
}

// ---- K1: q = attn_w.[emb|h0]+attn_b (waves 0..1023)
//          gh = w_hh.h0+b_hh          (waves 1024..4095) ----------------------
__global__ __launch_bounds__(256) void qgh_kernel(
    const int* __restrict__ token, const float* __restrict__ emb,
    const float* __restrict__ hidden, const float* __restrict__ attn_w,
    const float* __restrict__ attn_b, const float* __restrict__ w_hh,
    const float* __restrict__ b_hh, float* __restrict__ q,
    float* __restrict__ gh) {
    int w = (blockIdx.x * blockDim.x + threadIdx.x) >> 6;
    int lane = threadIdx.x & 63;
    if (w < HH) {
        const float* er = emb + (size_t)token[0] * II;
        const float* row = attn_w + (size_t)w * (II + HH);
        float acc = 0.f;
        for (int k = lane * 4; k < II + HH; k += 256) {
            float4 w4 = *(const float4*)(row + k);
            const float* src = (k < II) ? (er + k) : (hidden + (k - II));
            float4 x4 = *(const float4*)src;
            acc += w4.x * x4.x + w4.y * x4.y + w4.z * x4.z + w4.w * x4.w;
        }
        acc = wred_sum(acc);
        if (lane == 0) q[w] = acc + attn_b[w];
    } else {
        int r = w - HH;
        const float* row = w_hh + (size_t)r * HH;
        float acc = 0.f;
        for (int k = lane * 4; k < HH; k += 256) {
            float4 w4 = *(const float4*)(row + k);
            float4 x4 = *(const float4*)(hidden + k);
            acc += w4.x * x4.x + w4.y * x4.y + w4.z * x4.z + w4.w * x4.w;
        }
        acc = wred_sum(acc);
        if (lane == 0) gh[r] = acc + b_hh[r];
    }
}

// ---- K2: per block (64 rows): dot, row-norm, e=exp(cos-1) [fixed shift —
//      cosine sims are in [-1,1], so softmax max-pass is unnecessary],
//      then block-local UNNORMALIZED colsum partial + partial denominator ----
__global__ __launch_bounds__(1024) void simscol_kernel(
    const float* __restrict__ enc, const float* __restrict__ q,
    float* __restrict__ e_out, float* __restrict__ part,
    float* __restrict__ psum) {
    __shared__ float s_w[64];
    const int b = blockIdx.x, t = threadIdx.x;
    const int wv = t >> 6, lane = t & 63;

    // q into registers (each wave holds all 1024): q4[j] = q[lane*4 + j*256]
    float4 q4[4];
    #pragma unroll
    for (int j = 0; j < 4; ++j) q4[j] = *(const float4*)(q + lane * 4 + j * 256);
    // qn redundantly per wave (no sync needed)
    float ss = 0.f;
    #pragma unroll
    for (int j = 0; j < 4; ++j)
        ss += q4[j].x * q4[j].x + q4[j].y * q4[j].y + q4[j].z * q4[j].z +
              q4[j].w * q4[j].w;
    ss = wred_sum(ss);
    ss = __shfl(ss, 0);
    const float qn = fmaxf(sqrtf(ss), EPSF);

    // 4 rows per wave: dot + sumsq -> e
    #pragma unroll
    for (int j = 0; j < 4; ++j) {
        int r = b * 64 + wv * 4 + j;
        const float* row = enc + (size_t)r * HH;
        float dv = 0.f, sv = 0.f;
        #pragma unroll
        for (int k = 0; k < 4; ++k) {
            float4 e4 = *(const float4*)(row + lane * 4 + k * 256);
            dv += e4.x * q4[k].x + e4.y * q4[k].y + e4.z * q4[k].z +
                  e4.w * q4[k].w;
            sv += e4.x * e4.x + e4.y * e4.y + e4.z * e4.z + e4.w * e4.w;
        }
        #pragma unroll
        for (int o = 32; o; o >>= 1) {
            dv += __shfl_down(dv, o);
            sv += __shfl_down(sv, o);
        }
        if (lane == 0) {
            float en = fmaxf(sqrtf(sv), EPSF);
            float e = expf(dv / (qn * en) - 1.f);
            s_w[wv * 4 + j] = e;
            e_out[r] = e;
        }
    }
    __syncthreads();

    // partial denominator (wave 0)
    if (wv == 0) {
        float v = s_w[lane];
        v = wred_sum(v);
        if (lane == 0) psum[b] = v;
    }
    // block-local colsum over its 64 rows (L2-hot re-read); thread t = col t
    const float* base = enc + (size_t)b * 64 * HH;
    float acc = 0.f;
    #pragma unroll 8
    for (int r = 0; r < 64; ++r)
        acc = fmaf(s_w[r], base[(size_t)r * HH + t], acc);
    part[(size_t)b * HH + t] = acc;
}

// ---- K3: per block: reduce partials -> aa (redundant, folds 1/den),
//      write attn_weights (blocks 0..15), then x = relu(comb.[emb|aa]) -------
__global__ __launch_bounds__(1024) void xa_kernel(
    const int* __restrict__ token, const float* __restrict__ emb,
    const float* __restrict__ comb_w, const float* __restrict__ comb_b,
    const float* __restrict__ part, const float* __restrict__ psum,
    const float* __restrict__ e_in, float* __restrict__ x,
    float* __restrict__ attn_wout) {
    __shared__ float s_aa[HH];
    __shared__ float s_den;
    const int b = blockIdx.x, t = threadIdx.x;
    const int wv = t >> 6, lane = t & 63;

    if (wv == 0) {
        float v = psum[lane * 4] + psum[lane * 4 + 1] + psum[lane * 4 + 2] +
                  psum[lane * 4 + 3];
        v = wred_sum(v);
        if (lane == 0) s_den = v;
    }
    // redundant partial-reduce: thread t owns column t (1 MB L2 read / block)
    float acc = 0.f;
    for (int c = 0; c < 256; ++c) acc += part[(size_t)c * HH + t];
    __syncthreads();
    const float inv = 1.f / s_den;
    s_aa[t] = acc * inv;
    if (b < 16) attn_wout[b * 1024 + t] = e_in[b * 1024 + t] * inv;
    __syncthreads();

    // x row r = b*16 + wv
    int r = b * 16 + wv;
    const float* row = comb_w + (size_t)r * (II + HH);
    const float* er = emb + (size_t)token[0] * II;
    float a = 0.f;
    #pragma unroll
    for (int k = lane * 4; k < II; k += 256) {
        float4 w4 = *(const float4*)(row + k);
        float4 s4 = *(const float4*)(er + k);
        a += w4.x * s4.x + w4.y * s4.y + w4.z * s4.z + w4.w * s4.w;
    }
    #pragma unroll
    for (int k = lane * 4; k < HH; k += 256) {
        float4 w4 = *(const float4*)(row + II + k);
        a += w4.x * s_aa[k] + w4.y * s_aa[k + 1] + w4.z * s_aa[k + 2] +
             w4.w * s_aa[k + 3];
    }
    a = wred_sum(a);
    if (lane == 0) x[r] = fmaxf(a + comb_b[r], 0.f);
}

// ---- K4: gi = w_ih.x + b_ih (3072 rows, one wave per row) ------------------
__global__ __launch_bounds__(256) void gi_kernel(
    const float* __restrict__ w_ih, const float* __restrict__ x,
    const float* __restrict__ b_ih, float* __restrict__ gi) {
    int w = (blockIdx.x * blockDim.x + threadIdx.x) >> 6;
    int lane = threadIdx.x & 63;
    const float* row = w_ih + (size_t)w * II;
    float acc = 0.f;
    for (int k = lane * 4; k < II; k += 256) {
        float4 w4 = *(const float4*)(row + k);
        float4 x4 = *(const float4*)(x + k);
        acc += w4.x * x4.x + w4.y * x4.y + w4.z * x4.z + w4.w * x4.w;
    }
    acc = wred_sum(acc);
    if (lane == 0) gi[w] = acc + b_ih[w];
}

// ---- K5: GRU gates + fc2/relu + out scalar (single block, 256 thr) ---------
__global__ __launch_bounds__(256) void gruhead_kernel(
    const float* __restrict__ gi, const float* __restrict__ gh,
    const float* __restrict__ h0, const float* __restrict__ fc2_w,
    const float* __restrict__ fc2_b, const float* __restrict__ out_w,
    const float* __restrict__ out_b, float* __restrict__ h_new_out,
    float* __restrict__ out_scalar) {
    __shared__ float hsh[HH];
    __shared__ float f[64];
    int tid = threadIdx.x, wave = tid >> 6, lane = tid & 63;
    for (int i = tid; i < HH; i += 256) {
        float r = 1.f / (1.f + expf(-(gi[i] + gh[i])));
        float z = 1.f / (1.f + expf(-(gi[HH + i] + gh[HH + i])));
        float nn = tanhf(gi[2 * HH + i] + r * gh[2 * HH + i]);
        float h = (1.f - z) * nn + z * h0[i];
        h_new_out[i] = h;
        hsh[i] = h;
    }
    __syncthreads();
    for (int rr = 0; rr < 16; ++rr) {
        int r = wave * 16 + rr;
        const float* row = fc2_w + (size_t)r * HH;
        float acc = 0.f;
        for (int k = lane * 4; k < HH; k += 256) {
            float4 w4 = *(const float4*)(row + k);
            acc += w4.x * hsh[k] + w4.y * hsh[k + 1] + w4.z * hsh[k + 2] +
                   w4.w * hsh[k + 3];
        }
        acc = wred_sum(acc);
        if (lane == 0) f[r] = fmaxf(acc + fc2_b[r], 0.f);
    }
    __syncthreads();
    if (tid < 64) {
        float v = f[tid] * out_w[tid];
        v = wred_sum(v);
        if (tid == 0) out_scalar[0] = v + out_b[0];
    }
}

extern "C" void kernel_launch(void* const* d_in, const int* in_sizes, int n_in,
                              void* d_out, int out_size, void* d_ws,
                              size_t ws_size, hipStream_t stream) {
    const int*   token  = (const int*)d_in[0];
    const float* hidden = (const float*)d_in[1];
    const float* enc    = (const float*)d_in[2];
    const float* emb    = (const float*)d_in[3];
    const float* attn_w = (const float*)d_in[4];
    const float* attn_b = (const float*)d_in[5];
    const float* comb_w = (const float*)d_in[6];
    const float* comb_b = (const float*)d_in[7];
    const float* w_ih   = (const float*)d_in[8];
    const float* w_hh   = (const float*)d_in[9];
    const float* b_ih   = (const float*)d_in[10];
    const float* b_hh   = (const float*)d_in[11];
    const float* fc2_w  = (const float*)d_in[12];
    const float* fc2_b  = (const float*)d_in[13];
    const float* out_w  = (const float*)d_in[14];
    const float* out_b  = (const float*)d_in[15];

    float* ws = (float*)d_ws;
    float* q    = ws;           // 1024
    float* gh   = ws + 1024;    // 3072
    float* x    = ws + 4096;    // 1024
    float* gi   = ws + 5120;    // 3072
    float* e    = ws + 8192;    // 16384
    float* psum = ws + 24576;   // 256
    float* part = ws + 25600;   // 256*1024

    float* out_scalar = (float*)d_out;
    float* h_new      = (float*)d_out + 1;
    float* attn_wout  = (float*)d_out + 1 + HH;

    qgh_kernel<<<1024, 256, 0, stream>>>(token, emb, hidden, attn_w, attn_b,
                                         w_hh, b_hh, q, gh);
    simscol_kernel<<<256, 1024, 0, stream>>>(enc, q, e, part, psum);
    xa_kernel<<<64, 1024, 0, stream>>>(token, emb, comb_w, comb_b, part, psum,
                                       e, x, attn_wout);
    gi_kernel<<<768, 256, 0, stream>>>(w_ih, x, b_ih, gi);
    gruhead_kernel<<<1, 256, 0, stream>>>(gi, gh, hidden, fc2_w, fc2_b, out_w,
                                          out_b, h_new, out_scalar);
}

// Round 5
// 62.241 us; speedup vs baseline: 3.7563x; 1.2554x over previous
//
#include <hip/hip_runtime.h>
#include <hip/hip_bf16.h>
#include <math.h>

#define II 1024
#define HH 1024
#define LL 16384
#define EPSF 1e-8f
#define GI_BLOCKS 192u

__device__ __forceinline__ float wred_sum(float v) {
    #pragma unroll
    for (int o = 32; o; o >>= 1) v += __shfl_down(v, o);
    return v;
}

// ---- N1: q (waves 0..1023) | gh (1024..4095) | x_emb (4096..5119) ----------
// x_emb[r] = comb_w[r, :II] . emb_row + comb_b[r]  (attention-independent)
__global__ __launch_bounds__(256) void n1_kernel(
    const int* __restrict__ token, const float* __restrict__ emb,
    const float* __restrict__ hidden, const float* __restrict__ attn_w,
    const float* __restrict__ attn_b, const float* __restrict__ w_hh,
    const float* __restrict__ b_hh, const float* __restrict__ comb_w,
    const float* __restrict__ comb_b, float* __restrict__ q,
    float* __restrict__ gh, float* __restrict__ x_emb) {
    int w = (blockIdx.x * blockDim.x + threadIdx.x) >> 6;
    int lane = threadIdx.x & 63;
    const float* er = emb + (size_t)token[0] * II;
    if (w < HH) {  // q row
        const float* row = attn_w + (size_t)w * (II + HH);
        float acc = 0.f;
        for (int k = lane * 4; k < II + HH; k += 256) {
            float4 w4 = *(const float4*)(row + k);
            const float* src = (k < II) ? (er + k) : (hidden + (k - II));
            float4 x4 = *(const float4*)src;
            acc += w4.x * x4.x + w4.y * x4.y + w4.z * x4.z + w4.w * x4.w;
        }
        acc = wred_sum(acc);
        if (lane == 0) q[w] = acc + attn_b[w];
    } else if (w < HH + 3 * HH) {  // gh row
        int r = w - HH;
        const float* row = w_hh + (size_t)r * HH;
        float acc = 0.f;
        for (int k = lane * 4; k < HH; k += 256) {
            float4 w4 = *(const float4*)(row + k);
            float4 x4 = *(const float4*)(hidden + k);
            acc += w4.x * x4.x + w4.y * x4.y + w4.z * x4.z + w4.w * x4.w;
        }
        acc = wred_sum(acc);
        if (lane == 0) gh[r] = acc + b_hh[r];
    } else {  // x_emb row
        int r = w - 4 * HH;
        const float* row = comb_w + (size_t)r * (II + HH);
        float acc = 0.f;
        #pragma unroll
        for (int k = lane * 4; k < II; k += 256) {
            float4 w4 = *(const float4*)(row + k);
            float4 x4 = *(const float4*)(er + k);
            acc += w4.x * x4.x + w4.y * x4.y + w4.z * x4.z + w4.w * x4.w;
        }
        acc = wred_sum(acc);
        if (lane == 0) x_emb[r] = acc + comb_b[r];
    }
}

// ---- N2: per block (64 rows): dot, row-norm, e=exp(cos-1) [fixed shift —
//      cosine in [-1,1] so no max pass], block-local unnormalized colsum ----
__global__ __launch_bounds__(1024) void simscol_kernel(
    const float* __restrict__ enc, const float* __restrict__ q,
    float* __restrict__ e_out, float* __restrict__ part,
    float* __restrict__ psum) {
    __shared__ float s_w[64];
    const int b = blockIdx.x, t = threadIdx.x;
    const int wv = t >> 6, lane = t & 63;

    float4 q4[4];
    #pragma unroll
    for (int j = 0; j < 4; ++j) q4[j] = *(const float4*)(q + lane * 4 + j * 256);
    float ss = 0.f;
    #pragma unroll
    for (int j = 0; j < 4; ++j)
        ss += q4[j].x * q4[j].x + q4[j].y * q4[j].y + q4[j].z * q4[j].z +
              q4[j].w * q4[j].w;
    ss = wred_sum(ss);
    ss = __shfl(ss, 0);
    const float qn = fmaxf(sqrtf(ss), EPSF);

    #pragma unroll
    for (int j = 0; j < 4; ++j) {
        int r = b * 64 + wv * 4 + j;
        const float* row = enc + (size_t)r * HH;
        float dv = 0.f, sv = 0.f;
        #pragma unroll
        for (int k = 0; k < 4; ++k) {
            float4 e4 = *(const float4*)(row + lane * 4 + k * 256);
            dv += e4.x * q4[k].x + e4.y * q4[k].y + e4.z * q4[k].z +
                  e4.w * q4[k].w;
            sv += e4.x * e4.x + e4.y * e4.y + e4.z * e4.z + e4.w * e4.w;
        }
        #pragma unroll
        for (int o = 32; o; o >>= 1) {
            dv += __shfl_down(dv, o);
            sv += __shfl_down(sv, o);
        }
        if (lane == 0) {
            float en = fmaxf(sqrtf(sv), EPSF);
            float e = expf(dv / (qn * en) - 1.f);
            s_w[wv * 4 + j] = e;
            e_out[r] = e;
        }
    }
    __syncthreads();

    if (wv == 0) {
        float v = s_w[lane];
        v = wred_sum(v);
        if (lane == 0) psum[b] = v;
    }
    const float* base = enc + (size_t)b * 64 * HH;
    float acc = 0.f;
    #pragma unroll 8
    for (int r = 0; r < 64; ++r)
        acc = fmaf(s_w[r], base[(size_t)r * HH + t], acc);
    part[(size_t)b * HH + t] = acc;
}

// ---- N3: aa-reduce (redundant, float4 + LDS combine) + attn_weights out +
//      x = relu(x_emb + comb_w[:,II:] . aa) ----------------------------------
__global__ __launch_bounds__(1024) void n3_kernel(
    const float* __restrict__ comb_w, const float* __restrict__ part,
    const float* __restrict__ psum, const float* __restrict__ e_in,
    const float* __restrict__ x_emb, float* __restrict__ x,
    float* __restrict__ attn_wout) {
    __shared__ float s_tmp[4][1028];
    __shared__ float s_aa[HH];
    __shared__ float s_den;
    const int b = blockIdx.x, t = threadIdx.x;
    const int wv = t >> 6, lane = t & 63;

    if (wv == 0) {  // denominator from 256 psum entries
        float4 p4 = *(const float4*)(psum + lane * 4);
        float v = p4.x + p4.y + p4.z + p4.w;
        v = wred_sum(v);
        if (lane == 0) s_den = v;
    }
    // partial-reduce: cpart = t>>8 covers 64 of 256 chunks; col4 = t&255
    {
        int cpart = t >> 8, col4 = t & 255;
        const float4* p4 = (const float4*)part;
        float4 a = {0.f, 0.f, 0.f, 0.f};
        for (int c = cpart * 64; c < cpart * 64 + 64; ++c) {
            float4 v = p4[(size_t)c * 256 + col4];
            a.x += v.x; a.y += v.y; a.z += v.z; a.w += v.w;
        }
        s_tmp[cpart][col4 * 4 + 0] = a.x;
        s_tmp[cpart][col4 * 4 + 1] = a.y;
        s_tmp[cpart][col4 * 4 + 2] = a.z;
        s_tmp[cpart][col4 * 4 + 3] = a.w;
    }
    __syncthreads();
    const float inv = 1.f / s_den;
    s_aa[t] = (s_tmp[0][t] + s_tmp[1][t] + s_tmp[2][t] + s_tmp[3][t]) * inv;
    if (b < 16) attn_wout[b * 1024 + t] = e_in[b * 1024 + t] * inv;
    __syncthreads();

    // x row r = b*16 + wv (aa-half of comb_w only; emb-half precomputed in N1)
    int r = b * 16 + wv;
    const float* row = comb_w + (size_t)r * (II + HH) + II;
    float acc = 0.f;
    #pragma unroll
    for (int k = lane * 4; k < HH; k += 256) {
        float4 w4 = *(const float4*)(row + k);
        acc += w4.x * s_aa[k] + w4.y * s_aa[k + 1] + w4.z * s_aa[k + 2] +
               w4.w * s_aa[k + 3];
    }
    acc = wred_sum(acc);
    if (lane == 0) x[r] = fmaxf(acc + x_emb[r], 0.f);
}

// ---- N4: gi (192 blocks x 16 rows) + fan-in: last arriver does gru+fc2+out -
__global__ __launch_bounds__(1024) void n4_kernel(
    const float* __restrict__ w_ih, const float* __restrict__ x,
    const float* __restrict__ b_ih, float* __restrict__ gi,
    const float* __restrict__ gh, const float* __restrict__ hidden,
    const float* __restrict__ fc2_w, const float* __restrict__ fc2_b,
    const float* __restrict__ out_w, const float* __restrict__ out_b,
    float* __restrict__ h_new, float* __restrict__ out_scalar,
    unsigned* __restrict__ cnt) {
    __shared__ unsigned s_last;
    __shared__ float hsh[HH];
    __shared__ float f[64];
    const int b = blockIdx.x, t = threadIdx.x;
    const int wv = t >> 6, lane = t & 63;

    {   // gi row r = b*16 + wv
        int r = b * 16 + wv;
        const float* row = w_ih + (size_t)r * II;
        float acc = 0.f;
        #pragma unroll
        for (int k = lane * 4; k < II; k += 256) {
            float4 w4 = *(const float4*)(row + k);
            float4 x4 = *(const float4*)(x + k);
            acc += w4.x * x4.x + w4.y * x4.y + w4.z * x4.z + w4.w * x4.w;
        }
        acc = wred_sum(acc);
        if (lane == 0) gi[r] = acc + b_ih[r];
    }
    __syncthreads();
    if (t == 0) {
        __threadfence();  // release our gi stores
        unsigned old = atomicAdd(cnt, 1u);
        // exactly one multiple-of-192 crossing per call, any start value ->
        // deterministic, no reset node needed across graph replays
        s_last = ((old + 1u) % GI_BLOCKS == 0u) ? 1u : 0u;
    }
    __syncthreads();
    if (!s_last) return;
    __threadfence();  // acquire all blocks' gi stores

    // GRU gates
    float grv = gi[t] + gh[t];
    float gzv = gi[HH + t] + gh[HH + t];
    float rg = 1.f / (1.f + expf(-grv));
    float zg = 1.f / (1.f + expf(-gzv));
    float ng = tanhf(gi[2 * HH + t] + rg * gh[2 * HH + t]);
    float h = (1.f - zg) * ng + zg * hidden[t];
    hsh[t] = h;
    h_new[t] = h;
    __syncthreads();
    // fc2: 16 waves x 4 rows
    #pragma unroll
    for (int rr = 0; rr < 4; ++rr) {
        int r2 = wv * 4 + rr;
        const float* row = fc2_w + (size_t)r2 * HH;
        float acc = 0.f;
        #pragma unroll
        for (int k = lane * 4; k < HH; k += 256) {
            float4 w4 = *(const float4*)(row + k);
            acc += w4.x * hsh[k] + w4.y * hsh[k + 1] + w4.z * hsh[k + 2] +
                   w4.w * hsh[k + 3];
        }
        acc = wred_sum(acc);
        if (lane == 0) f[r2] = fmaxf(acc + fc2_b[r2], 0.f);
    }
    __syncthreads();
    if (t < 64) {
        float v = f[t] * out_w[t];
        v = wred_sum(v);
        if (t == 0) out_scalar[0] = v + out_b[0];
    }
}

extern "C" void kernel_launch(void* const* d_in, const int* in_sizes, int n_in,
                              void* d_out, int out_size, void* d_ws,
                              size_t ws_size, hipStream_t stream) {
    const int*   token  = (const int*)d_in[0];
    const float* hidden = (const float*)d_in[1];
    const float* enc    = (const float*)d_in[2];
    const float* emb    = (const float*)d_in[3];
    const float* attn_w = (const float*)d_in[4];
    const float* attn_b = (const float*)d_in[5];
    const float* comb_w = (const float*)d_in[6];
    const float* comb_b = (const float*)d_in[7];
    const float* w_ih   = (const float*)d_in[8];
    const float* w_hh   = (const float*)d_in[9];
    const float* b_ih   = (const float*)d_in[10];
    const float* b_hh   = (const float*)d_in[11];
    const float* fc2_w  = (const float*)d_in[12];
    const float* fc2_b  = (const float*)d_in[13];
    const float* out_w  = (const float*)d_in[14];
    const float* out_b  = (const float*)d_in[15];

    float* ws = (float*)d_ws;
    float* q     = ws;            // 1024
    float* gh    = ws + 1024;     // 3072
    float* x_emb = ws + 4096;     // 1024
    float* x     = ws + 5120;     // 1024
    float* gi    = ws + 6144;     // 3072
    float* e     = ws + 9216;     // 16384
    float* psum  = ws + 25600;    // 256
    float* part  = ws + 26624;    // 256*1024
    unsigned* cnt = (unsigned*)(ws + 26624 + 262144);  // 1 (never reset)

    float* out_scalar = (float*)d_out;
    float* h_new      = (float*)d_out + 1;
    float* attn_wout  = (float*)d_out + 1 + HH;

    // N1: q + gh + x_emb (5120 waves)
    n1_kernel<<<1280, 256, 0, stream>>>(token, emb, hidden, attn_w, attn_b,
                                        w_hh, b_hh, comb_w, comb_b, q, gh,
                                        x_emb);
    // N2: sims + colsum partials
    simscol_kernel<<<256, 1024, 0, stream>>>(enc, q, e, part, psum);
    // N3: aa + attn_weights + x
    n3_kernel<<<64, 1024, 0, stream>>>(comb_w, part, psum, e, x_emb, x,
                                       attn_wout);
    // N4: gi + fan-in gru/fc2/out
    n4_kernel<<<GI_BLOCKS, 1024, 0, stream>>>(w_ih, x, b_ih, gi, gh, hidden,
                                              fc2_w, fc2_b, out_w, out_b,
                                              h_new, out_scalar, cnt);
}